// Round 19
// baseline (109.875 us; speedup 1.0000x reference)
//
#include <hip/hip_runtime.h>
#include <hip/hip_bf16.h>

// DirectionalSeparableConv2D — round 19: per-kb MFMA interleaved into the
// chunk loop. r18 (97.7us, passed) left a serial phase chain: MFMA tail ran
// after all staging; DMA drains exposed each chunk. Here acc[2][12] persists
// across the loop; after chunks 2kb,2kb+1 land in yT, that kb's MFMA batch
// runs in-loop. Odd-t iterations defer the DMA drain until after the MFMA
// (lgkm-only barrier publishes yT without draining vmcnt — r14-proven
// machinery). Tail = stores only. All data mappings bit-identical to r18
// (stage / dwconv / transpose / yT swizzle / frag layout / XCD swizzle).
// Risk: +96 acc VGPRs; spill signature = VGPR<=128 + WRITE_SIZE >> 147MB.

namespace {
constexpr int HH = 48, WW = 48, HW = HH * WW;
constexpr int C_IN = 128, C_OUT = 128, NB = 128;
constexpr int RPB = 8;                  // stripe rows per block
constexpr int NSTR = HH / RPB;          // 6
constexpr int PIX = RPB * WW;           // 384
constexpr int NT = 512;
constexpr int CHK = 16;                 // channels per chunk
constexpr int NCHK = C_IN / CHK;        // 8
constexpr int XR = RPB + 4;             // 12 staged rows
constexpr int QR = 17;                  // quads per staged row (12 data + 5 zero)
constexpr int XROWF = QR * 4;           // 68 floats per row
constexpr int XQ = CHK * XR * QR;       // 3264 quads
constexpr int YCS = 392;                // ycp row stride (ushorts)
constexpr int NBLK = NB * NSTR;         // 768 = 8 * 96
constexpr size_t M_BYTES = 128 * 128 * 2;
constexpr size_t ZB_OFF = M_BYTES;
}

typedef __attribute__((ext_vector_type(8))) short bf16x8;
typedef __attribute__((ext_vector_type(4))) float f32x4;

__device__ __forceinline__ ushort f2bf(float f) {
    __hip_bfloat16 h = __float2bfloat16(f);
    return *reinterpret_cast<ushort*>(&h);
}

#define SFENCE() __builtin_amdgcn_sched_barrier(0)

// ======================= k0: build M_bf[o][c] (bf16) =======================
__global__ void build_M(const float* __restrict__ c2c, const float* __restrict__ p2c,
                        const float* __restrict__ d2c, const float* __restrict__ c2d,
                        const float* __restrict__ d2dW, ushort* __restrict__ Mbf) {
    int t = blockIdx.x * 256 + threadIdx.x;
    if (t >= 128 * 128) return;
    int o = t & 127, c = t >> 7;
    float v;
    if (o < 32) {
        if (c < 32)       v = c2c[o * 32 + c];
        else if (c < 56)  v = p2c[o * 24 + c - 32];
        else if (c < 80)  v = p2c[o * 24 + c - 56];
        else if (c < 104) v = d2c[o * 24 + c - 80];
        else              v = d2c[o * 24 + c - 104];
    } else {
        int g = (o - 32) / 24, oo = (o - 32) % 24;
        if (c < 32) v = c2d[oo * 32 + c];
        else {
            int gc = (c - 32) / 24, cc2 = (c - 32) % 24;
            v = (gc == g) ? d2dW[oo * 24 + cc2] : 0.f;
        }
    }
    Mbf[o * 128 + c] = f2bf(v);
}

// ======================= fused kernel =======================
__global__ __launch_bounds__(NT) void dsc_fused(
    const float* __restrict__ x,
    const float* __restrict__ cen_t,   // [32,3,3]
    const float* __restrict__ dir_t,   // [24,5]
    const ushort* __restrict__ Mbf,    // bf16 [128o][128c]
    const float* __restrict__ zb,      // 16B zero block
    float* __restrict__ out)
{
    __shared__ float  xs[XQ * 4];           // 52224 B  (single buffer)
    __shared__ ushort yT[PIX * 128];        // 98304 B, granule-XOR swizzled
    __shared__ ushort ycp[CHK * YCS];       // 12544 B       (total 163072)

    const int tid = threadIdx.x;
    // Bijective XCD swizzle: 768 = 8 * 96 exactly.
    const int bid = (blockIdx.x & 7) * (NBLK / 8) + (blockIdx.x >> 3);
    const int b   = bid / NSTR;
    const int h0  = (bid % NSTR) * RPB;
    const float* __restrict__ xb = x + (size_t)b * C_IN * HW;

    const int l     = tid & 63;
    const int wv    = tid >> 6;             // 0..7
    const int ofr   = wv & 3;
    const int phalf = wv >> 2;

    // ---- stage chunk t: 3264 quads, dest linear ----
    auto stage = [&](int t) {
        const int c0 = t * CHK;
#pragma unroll
        for (int k = 0; k < 7; ++k) {
            int d = tid + k * NT;
            if (d < XQ) {
                int q  = d % QR;
                int cr = d / QR;
                int r  = cr % XR;
                int c  = cr / XR;
                int gh = h0 - 2 + r;
                bool ok = ((unsigned)gh < (unsigned)HH) && (q < 12);
                const float* src = ok ? (xb + (size_t)(c0 + c) * HW + gh * WW + q * 4) : zb;
                __builtin_amdgcn_global_load_lds(
                    (const __attribute__((address_space(1))) unsigned int*)src,
                    (__attribute__((address_space(3))) unsigned int*)(xs + (size_t)d * 4),
                    16, 0, 0);
            }
        }
    };

    // ---- dwconv chunk t: 768 eight-pixel tasks -> ycp (one b128/task) ----
    auto dwconv = [&](int t) {
        const int c0 = t * CHK;
#pragma unroll
        for (int k = 0; k < 2; ++k) {
            int task = tid + k * NT;
            if (task >= CHK * 48) break;
            int c   = task / 48;
            int pg  = task % 48;
            int row = pg & 7;
            int w0  = (pg >> 3) * 8;          // 0,8,..,40
            int cc  = c0 + c;
            const float* xr0 = xs + (size_t)(c * XR) * XROWF;
            float acv[8];
#pragma unroll
            for (int j = 0; j < 8; ++j) acv[j] = 0.f;

            if (cc < 32) {                     // 3x3: taps win[j+3..j+5]
#pragma unroll
                for (int i = 0; i < 3; ++i) {
                    const float* xr = xr0 + (row + 1 + i) * XROWF;
                    float4 A = *(const float4*)&xr[(w0 - 4) & 63];
                    float4 B = *(const float4*)&xr[w0];
                    float4 C = *(const float4*)&xr[w0 + 4];
                    float4 D = *(const float4*)&xr[(w0 + 8) & 63];
                    float win[16] = {A.x,A.y,A.z,A.w, B.x,B.y,B.z,B.w,
                                     C.x,C.y,C.z,C.w, D.x,D.y,D.z,D.w};
                    float k0 = cen_t[cc*9 + i*3 + 0];
                    float k1 = cen_t[cc*9 + i*3 + 1];
                    float k2 = cen_t[cc*9 + i*3 + 2];
#pragma unroll
                    for (int j = 0; j < 8; ++j)
                        acv[j] += k0*win[j+3] + k1*win[j+4] + k2*win[j+5];
                }
            } else if (cc < 56) {              // h: taps win[j+2+i]
                int cd = cc - 32;
                const float* xr = xr0 + (row + 2) * XROWF;
                float4 A = *(const float4*)&xr[(w0 - 4) & 63];
                float4 B = *(const float4*)&xr[w0];
                float4 C = *(const float4*)&xr[w0 + 4];
                float4 D = *(const float4*)&xr[(w0 + 8) & 63];
                float win[16] = {A.x,A.y,A.z,A.w, B.x,B.y,B.z,B.w,
                                 C.x,C.y,C.z,C.w, D.x,D.y,D.z,D.w};
#pragma unroll
                for (int i = 0; i < 5; ++i) {
                    float tt = dir_t[cd*5 + i];
#pragma unroll
                    for (int j = 0; j < 8; ++j) acv[j] += tt * win[j+2+i];
                }
            } else if (cc < 80) {              // v: 2 quads per row
                int cd = cc - 56;
#pragma unroll
                for (int i = 0; i < 5; ++i) {
                    const float* xr = xr0 + (row + i) * XROWF;
                    float4 B = *(const float4*)&xr[w0];
                    float4 C = *(const float4*)&xr[w0 + 4];
                    float w8[8] = {B.x,B.y,B.z,B.w, C.x,C.y,C.z,C.w};
                    float tt = dir_t[cd*5 + i];
#pragma unroll
                    for (int j = 0; j < 8; ++j) acv[j] += tt * w8[j];
                }
            } else {                           // d1 / d2
                int cd  = (cc < 104) ? cc - 80 : cc - 104;
                bool d1 = (cc < 104);
#pragma unroll
                for (int i = 0; i < 5; ++i) {
                    const float* xr = xr0 + (row + i) * XROWF;
                    float4 A = *(const float4*)&xr[(w0 - 4) & 63];
                    float4 B = *(const float4*)&xr[w0];
                    float4 C = *(const float4*)&xr[w0 + 4];
                    float4 D = *(const float4*)&xr[(w0 + 8) & 63];
                    float win[16] = {A.x,A.y,A.z,A.w, B.x,B.y,B.z,B.w,
                                     C.x,C.y,C.z,C.w, D.x,D.y,D.z,D.w};
                    float tt = dir_t[cd*5 + i];
                    if (d1) {
#pragma unroll
                        for (int j = 0; j < 8; ++j) acv[j] += tt * win[j+2+i];
                    } else {
#pragma unroll
                        for (int j = 0; j < 8; ++j) acv[j] += tt * win[j+6-i];
                    }
                }
            }

            union { ushort us[8]; uint4 v4; } s;
#pragma unroll
            for (int j = 0; j < 8; ++j) s.us[j] = f2bf(acv[j]);
            *(uint4*)&ycp[c * YCS + row * 48 + w0] = s.v4;   // 16B aligned
        }
    };

    // ---- transpose chunk t: gather 8 ch of one px -> b128 into yT ----
    auto transpose = [&](int t) {
#pragma unroll
        for (int k = 0; k < 2; ++k) {
            int task = tid + k * NT;
            if (task >= 2 * PIX) break;
            int gg = task / PIX;               // chunk-local granule 0..1
            int p  = task % PIX;
            int g  = t * 2 + gg;               // global granule 0..15
            union { ushort us[8]; uint4 v4; } s;
#pragma unroll
            for (int j = 0; j < 8; ++j) s.us[j] = ycp[(gg * 8 + j) * YCS + p];
            int byte = p * 256 + ((g ^ (p & 7)) << 4);
            *(uint4*)((char*)yT + byte) = s.v4;
        }
    };

    // ---- persistent accumulators: [pass][pf], kb accumulated in-loop ----
    f32x4 acc[2][12] = {};

    // ---- MFMA batch for one kb (32 channels = chunks 2kb, 2kb+1) ----
    auto mfma_kb = [&](int kb) {
        int g = kb * 4 + (l >> 4);
#pragma unroll
        for (int pf = 0; pf < 12; ++pf) {
            int p = (phalf * 12 + pf) * 16 + (l & 15);
            const bf16x8 bfr = *(const bf16x8*)((const char*)yT + p * 256 + ((g ^ (p & 7)) << 4));
#pragma unroll
            for (int pass = 0; pass < 2; ++pass) {
                int o0 = pass * 64 + ofr * 16;
                bf16x8 a = *(const bf16x8*)(Mbf + (o0 + (l & 15)) * 128 + kb * 32 + (l >> 4) * 8);
                acc[pass][pf] = __builtin_amdgcn_mfma_f32_16x16x32_bf16(a, bfr, acc[pass][pf], 0, 0, 0);
            }
        }
    };

    // ================= interleaved pipeline =================
    stage(0);
    __syncthreads();
    for (int t = 0; t < NCHK; ++t) {
        dwconv(t);
        __syncthreads();                       // xs reads + ycp writes done
        if (t + 1 < NCHK) stage(t + 1);        // DMA into xs (reads drained)
        transpose(t);
        // publish yT without draining the DMA:
        asm volatile("s_waitcnt lgkmcnt(0)" ::: "memory");
        SFENCE();
        __builtin_amdgcn_s_barrier();
        SFENCE();
        if (t & 1) mfma_kb(t >> 1);            // overlaps in-flight DMA
        // drain DMA before next dwconv reads xs:
        asm volatile("s_waitcnt vmcnt(0)" ::: "memory");
        SFENCE();
        __builtin_amdgcn_s_barrier();
        SFENCE();
    }

    // ================= tail: stores only =================
    float* __restrict__ ob = out + (size_t)b * C_OUT * HW + h0 * WW;
#pragma unroll
    for (int pass = 0; pass < 2; ++pass) {
        int o0 = pass * 64 + ofr * 16;
#pragma unroll
        for (int pf = 0; pf < 12; ++pf) {
            int p = (phalf * 12 + pf) * 16 + (l & 15);
            int obase = o0 + (l >> 4) * 4;
#pragma unroll
            for (int r = 0; r < 4; ++r)
                ob[(size_t)(obase + r) * HW + p] = acc[pass][pf][r];
        }
    }
}

// ======================= launcher =======================
extern "C" void kernel_launch(void* const* d_in, const int* in_sizes, int n_in,
                              void* d_out, int out_size, void* d_ws, size_t ws_size,
                              hipStream_t stream) {
    const float* x     = (const float*)d_in[0];
    const float* cen_t = (const float*)d_in[1];
    const float* dir_t = (const float*)d_in[2];
    const float* c2c   = (const float*)d_in[3];
    const float* p2c   = (const float*)d_in[4];
    const float* d2c   = (const float*)d_in[5];
    const float* c2d   = (const float*)d_in[6];
    const float* d2dW  = (const float*)d_in[7];
    float* out = (float*)d_out;

    ushort* Mbf = (ushort*)d_ws;                       // 32 KiB
    float*  zb  = (float*)((char*)d_ws + ZB_OFF);      // 16 B zero block

    hipMemsetAsync(zb, 0, 64, stream);                 // ws is poisoned each run
    build_M<<<64, 256, 0, stream>>>(c2c, p2c, d2c, c2d, d2dW, Mbf);
    dsc_fused<<<NBLK, NT, 0, stream>>>(x, cen_t, dir_t, Mbf, zb, out);
}

// Round 21
// 96.357 us; speedup vs baseline: 1.1403x; 1.1403x over previous
//
#include <hip/hip_runtime.h>
#include <hip/hip_bf16.h>

// DirectionalSeparableConv2D — round 21: r18 base (passed, 97.7us) with a
// deduplicated MFMA tail. r16/r17/r20 (2-blocks/CU family) all failed absmax
// ~0.07-0.09 with paper-correct mappings — branch abandoned (3 strikes).
// Tail fix: old tail read each yT B-frag twice (once per o-pass, 96 b128
// reads/thread); new tail loads all 8 A-frags upfront and reads each bfr
// once, feeding both passes (48 reads). acc[2][12] tail-local (r19 proved
// no-spill at 112 VGPR). Everything before the tail is byte-identical to r18.

namespace {
constexpr int HH = 48, WW = 48, HW = HH * WW;
constexpr int C_IN = 128, C_OUT = 128, NB = 128;
constexpr int RPB = 8;                  // stripe rows per block
constexpr int NSTR = HH / RPB;          // 6
constexpr int PIX = RPB * WW;           // 384
constexpr int NT = 512;
constexpr int CHK = 16;                 // channels per chunk
constexpr int NCHK = C_IN / CHK;        // 8
constexpr int XR = RPB + 4;             // 12 staged rows
constexpr int QR = 17;                  // quads per staged row (12 data + 5 zero)
constexpr int XROWF = QR * 4;           // 68 floats per row
constexpr int XQ = CHK * XR * QR;       // 3264 quads
constexpr int YCS = 392;                // ycp row stride (ushorts)
constexpr int NBLK = NB * NSTR;         // 768 = 8 * 96
constexpr size_t M_BYTES = 128 * 128 * 2;
constexpr size_t ZB_OFF = M_BYTES;
}

typedef __attribute__((ext_vector_type(8))) short bf16x8;
typedef __attribute__((ext_vector_type(4))) float f32x4;

__device__ __forceinline__ ushort f2bf(float f) {
    __hip_bfloat16 h = __float2bfloat16(f);
    return *reinterpret_cast<ushort*>(&h);
}

// ======================= k0: build M_bf[o][c] (bf16) =======================
__global__ void build_M(const float* __restrict__ c2c, const float* __restrict__ p2c,
                        const float* __restrict__ d2c, const float* __restrict__ c2d,
                        const float* __restrict__ d2dW, ushort* __restrict__ Mbf) {
    int t = blockIdx.x * 256 + threadIdx.x;
    if (t >= 128 * 128) return;
    int o = t & 127, c = t >> 7;
    float v;
    if (o < 32) {
        if (c < 32)       v = c2c[o * 32 + c];
        else if (c < 56)  v = p2c[o * 24 + c - 32];
        else if (c < 80)  v = p2c[o * 24 + c - 56];
        else if (c < 104) v = d2c[o * 24 + c - 80];
        else              v = d2c[o * 24 + c - 104];
    } else {
        int g = (o - 32) / 24, oo = (o - 32) % 24;
        if (c < 32) v = c2d[oo * 32 + c];
        else {
            int gc = (c - 32) / 24, cc2 = (c - 32) % 24;
            v = (gc == g) ? d2dW[oo * 24 + cc2] : 0.f;
        }
    }
    Mbf[o * 128 + c] = f2bf(v);
}

// ======================= fused kernel =======================
__global__ __launch_bounds__(NT) void dsc_fused(
    const float* __restrict__ x,
    const float* __restrict__ cen_t,   // [32,3,3]
    const float* __restrict__ dir_t,   // [24,5]
    const ushort* __restrict__ Mbf,    // bf16 [128o][128c]
    const float* __restrict__ zb,      // 16B zero block
    float* __restrict__ out)
{
    __shared__ float  xs[XQ * 4];           // 52224 B  (single buffer)
    __shared__ ushort yT[PIX * 128];        // 98304 B, granule-XOR swizzled
    __shared__ ushort ycp[CHK * YCS];       // 12544 B       (total 163072)

    const int tid = threadIdx.x;
    // Bijective XCD swizzle: 768 = 8 * 96 exactly.
    const int bid = (blockIdx.x & 7) * (NBLK / 8) + (blockIdx.x >> 3);
    const int b   = bid / NSTR;
    const int h0  = (bid % NSTR) * RPB;
    const float* __restrict__ xb = x + (size_t)b * C_IN * HW;

    // ---- stage chunk t: 3264 quads, dest linear ----
    auto stage = [&](int t) {
        const int c0 = t * CHK;
#pragma unroll
        for (int k = 0; k < 7; ++k) {
            int d = tid + k * NT;
            if (d < XQ) {
                int q  = d % QR;
                int cr = d / QR;
                int r  = cr % XR;
                int c  = cr / XR;
                int gh = h0 - 2 + r;
                bool ok = ((unsigned)gh < (unsigned)HH) && (q < 12);
                const float* src = ok ? (xb + (size_t)(c0 + c) * HW + gh * WW + q * 4) : zb;
                __builtin_amdgcn_global_load_lds(
                    (const __attribute__((address_space(1))) unsigned int*)src,
                    (__attribute__((address_space(3))) unsigned int*)(xs + (size_t)d * 4),
                    16, 0, 0);
            }
        }
    };

    // ---- dwconv chunk t: 768 eight-pixel tasks -> ycp (one b128/task) ----
    auto dwconv = [&](int t) {
        const int c0 = t * CHK;
#pragma unroll
        for (int k = 0; k < 2; ++k) {
            int task = tid + k * NT;
            if (task >= CHK * 48) break;
            int c   = task / 48;
            int pg  = task % 48;
            int row = pg & 7;
            int w0  = (pg >> 3) * 8;          // 0,8,..,40
            int cc  = c0 + c;
            const float* xr0 = xs + (size_t)(c * XR) * XROWF;
            float acv[8];
#pragma unroll
            for (int j = 0; j < 8; ++j) acv[j] = 0.f;

            if (cc < 32) {                     // 3x3: taps win[j+3..j+5]
#pragma unroll
                for (int i = 0; i < 3; ++i) {
                    const float* xr = xr0 + (row + 1 + i) * XROWF;
                    float4 A = *(const float4*)&xr[(w0 - 4) & 63];
                    float4 B = *(const float4*)&xr[w0];
                    float4 C = *(const float4*)&xr[w0 + 4];
                    float4 D = *(const float4*)&xr[(w0 + 8) & 63];
                    float win[16] = {A.x,A.y,A.z,A.w, B.x,B.y,B.z,B.w,
                                     C.x,C.y,C.z,C.w, D.x,D.y,D.z,D.w};
                    float k0 = cen_t[cc*9 + i*3 + 0];
                    float k1 = cen_t[cc*9 + i*3 + 1];
                    float k2 = cen_t[cc*9 + i*3 + 2];
#pragma unroll
                    for (int j = 0; j < 8; ++j)
                        acv[j] += k0*win[j+3] + k1*win[j+4] + k2*win[j+5];
                }
            } else if (cc < 56) {              // h: taps win[j+2+i]
                int cd = cc - 32;
                const float* xr = xr0 + (row + 2) * XROWF;
                float4 A = *(const float4*)&xr[(w0 - 4) & 63];
                float4 B = *(const float4*)&xr[w0];
                float4 C = *(const float4*)&xr[w0 + 4];
                float4 D = *(const float4*)&xr[(w0 + 8) & 63];
                float win[16] = {A.x,A.y,A.z,A.w, B.x,B.y,B.z,B.w,
                                 C.x,C.y,C.z,C.w, D.x,D.y,D.z,D.w};
#pragma unroll
                for (int i = 0; i < 5; ++i) {
                    float tt = dir_t[cd*5 + i];
#pragma unroll
                    for (int j = 0; j < 8; ++j) acv[j] += tt * win[j+2+i];
                }
            } else if (cc < 80) {              // v: 2 quads per row
                int cd = cc - 56;
#pragma unroll
                for (int i = 0; i < 5; ++i) {
                    const float* xr = xr0 + (row + i) * XROWF;
                    float4 B = *(const float4*)&xr[w0];
                    float4 C = *(const float4*)&xr[w0 + 4];
                    float w8[8] = {B.x,B.y,B.z,B.w, C.x,C.y,C.z,C.w};
                    float tt = dir_t[cd*5 + i];
#pragma unroll
                    for (int j = 0; j < 8; ++j) acv[j] += tt * w8[j];
                }
            } else {                           // d1 / d2
                int cd  = (cc < 104) ? cc - 80 : cc - 104;
                bool d1 = (cc < 104);
#pragma unroll
                for (int i = 0; i < 5; ++i) {
                    const float* xr = xr0 + (row + i) * XROWF;
                    float4 A = *(const float4*)&xr[(w0 - 4) & 63];
                    float4 B = *(const float4*)&xr[w0];
                    float4 C = *(const float4*)&xr[w0 + 4];
                    float4 D = *(const float4*)&xr[(w0 + 8) & 63];
                    float win[16] = {A.x,A.y,A.z,A.w, B.x,B.y,B.z,B.w,
                                     C.x,C.y,C.z,C.w, D.x,D.y,D.z,D.w};
                    float tt = dir_t[cd*5 + i];
                    if (d1) {
#pragma unroll
                        for (int j = 0; j < 8; ++j) acv[j] += tt * win[j+2+i];
                    } else {
#pragma unroll
                        for (int j = 0; j < 8; ++j) acv[j] += tt * win[j+6-i];
                    }
                }
            }

            union { ushort us[8]; uint4 v4; } s;
#pragma unroll
            for (int j = 0; j < 8; ++j) s.us[j] = f2bf(acv[j]);
            *(uint4*)&ycp[c * YCS + row * 48 + w0] = s.v4;   // 16B aligned
        }
    };

    // ---- transpose chunk t: gather 8 ch of one px -> b128 into yT ----
    auto transpose = [&](int t) {
#pragma unroll
        for (int k = 0; k < 2; ++k) {
            int task = tid + k * NT;
            if (task >= 2 * PIX) break;
            int gg = task / PIX;               // chunk-local granule 0..1
            int p  = task % PIX;
            int g  = t * 2 + gg;               // global granule 0..15
            union { ushort us[8]; uint4 v4; } s;
#pragma unroll
            for (int j = 0; j < 8; ++j) s.us[j] = ycp[(gg * 8 + j) * YCS + p];
            int byte = p * 256 + ((g ^ (p & 7)) << 4);
            *(uint4*)((char*)yT + byte) = s.v4;
        }
    };

    // ================= channel-streamed dwconv =================
    stage(0);
    __syncthreads();
    for (int t = 0; t < NCHK; ++t) {
        dwconv(t);
        __syncthreads();                       // xs reads + ycp writes done
        if (t + 1 < NCHK) stage(t + 1);        // DMA overlaps transpose
        transpose(t);
        __syncthreads();                       // DMA drained; ycp free
    }

    // ================= MFMA tail: 8 waves, dedup'd B-frags =================
    const int l     = tid & 63;
    const int wv    = tid >> 6;                // 0..7
    const int ofr   = wv & 3;
    const int phalf = wv >> 2;
    float* __restrict__ ob = out + (size_t)b * C_OUT * HW + h0 * WW;

    // all 8 A-frags upfront (independent L2-hot loads, pipelined)
    bf16x8 afr[2][4];
#pragma unroll
    for (int pass = 0; pass < 2; ++pass)
#pragma unroll
        for (int kb = 0; kb < 4; ++kb) {
            int o0 = pass * 64 + ofr * 16;
            afr[pass][kb] = *(const bf16x8*)(Mbf + (o0 + (l & 15)) * 128 + kb * 32 + (l >> 4) * 8);
        }

    f32x4 acc[2][12] = {};
#pragma unroll
    for (int kb = 0; kb < 4; ++kb) {
        int g = kb * 4 + (l >> 4);
#pragma unroll
        for (int pf = 0; pf < 12; ++pf) {
            int p = (phalf * 12 + pf) * 16 + (l & 15);
            const bf16x8 bfr = *(const bf16x8*)((const char*)yT + p * 256 + ((g ^ (p & 7)) << 4));
            acc[0][pf] = __builtin_amdgcn_mfma_f32_16x16x32_bf16(afr[0][kb], bfr, acc[0][pf], 0, 0, 0);
            acc[1][pf] = __builtin_amdgcn_mfma_f32_16x16x32_bf16(afr[1][kb], bfr, acc[1][pf], 0, 0, 0);
        }
    }

#pragma unroll
    for (int pass = 0; pass < 2; ++pass) {
        int o0 = pass * 64 + ofr * 16;
#pragma unroll
        for (int pf = 0; pf < 12; ++pf) {
            int p = (phalf * 12 + pf) * 16 + (l & 15);
            int obase = o0 + (l >> 4) * 4;
#pragma unroll
            for (int r = 0; r < 4; ++r)
                ob[(size_t)(obase + r) * HW + p] = acc[pass][pf][r];
        }
    }
}

// ======================= launcher =======================
extern "C" void kernel_launch(void* const* d_in, const int* in_sizes, int n_in,
                              void* d_out, int out_size, void* d_ws, size_t ws_size,
                              hipStream_t stream) {
    const float* x     = (const float*)d_in[0];
    const float* cen_t = (const float*)d_in[1];
    const float* dir_t = (const float*)d_in[2];
    const float* c2c   = (const float*)d_in[3];
    const float* p2c   = (const float*)d_in[4];
    const float* d2c   = (const float*)d_in[5];
    const float* c2d   = (const float*)d_in[6];
    const float* d2dW  = (const float*)d_in[7];
    float* out = (float*)d_out;

    ushort* Mbf = (ushort*)d_ws;                       // 32 KiB
    float*  zb  = (float*)((char*)d_ws + ZB_OFF);      // 16 B zero block

    hipMemsetAsync(zb, 0, 64, stream);                 // ws is poisoned each run
    build_M<<<64, 256, 0, stream>>>(c2c, p2c, d2c, c2d, d2dW, Mbf);
    dsc_fused<<<NBLK, NT, 0, stream>>>(x, cen_t, dir_t, Mbf, zb, out);
}